// Round 7
// baseline (1148.343 us; speedup 1.0000x reference)
//
#include <hip/hip_runtime.h>
#include <math.h>
#include <stdint.h>

// SLAYER 2-layer SNN. Round 19: cap conv_fir at 128 VGPR.
//   expand_x -> decompose_i8 x2 ->
//   gemm<1024> -> conv_fir -> scan<BITS->Bexp2> ->
//   gemm<2048> -> conv_fir -> scan<F32>.
// R18 post-mortem: split succeeded for gemm (128-cap held, not in top-5),
// but conv_fir inherited the disease: natural alloc 196 VGPR (compiler
// interleaves the 4 unrolled FIR passes -> 4 fp64 chains of ILP) -> 2
// waves/SIMD -> 216us latency-bound (VALUBusy 23%, HBM 12%, floor ~40us).
// R19: amdgpu_num_vgpr(128) on conv_fir. True live set ~60 (4 acc + 4 av +
// 4 taps + rotation) -- cap is slack, unlike R15's gemm (needed 140+).
// Trades 4-way cross-pass ILP for 2x resident waves; 4 waves/SIMD matches
// the 35KB-LDS 4-blocks/CU cap (64-VGPR would buy nothing more).
// Gate: conv WRITE_SIZE stays exactly 131072 KB / FETCH ~65 MB, else revert.
// Numerics byte-identical (absmax 0.0): attribute only.

#define TT     256
#define KLEN   62
#define THETA  10.0

typedef int v4i __attribute__((ext_vector_type(4)));

// ===================== expand x -> i8 B-matrix (layer 1) ====================
// x: [32][1024][256] f32 {0,1}; bexp: [b][g=i/16][t][m=i%16] i8 {0,1}
__global__ __launch_bounds__(256)
void expand_x(const float* __restrict__ x, signed char* __restrict__ bexp)
{
    const int b = blockIdx.x;
    const int g = blockIdx.y;             // 64 groups of 16 inputs
    const int t = threadIdx.x;
    const float* xp = x + ((size_t)b*1024 + g*16)*TT + t;
    uint32_t uu[4];
    #pragma unroll
    for (int j = 0; j < 4; ++j) {
        uint32_t w = 0;
        #pragma unroll
        for (int m = 0; m < 4; ++m)
            w |= (xp[(size_t)(j*4 + m)*TT] >= 0.5f) ? (1u << (8*m)) : 0u;
        uu[j] = w;
    }
    *(uint4*)(bexp + (((size_t)b*64 + g)*256 + t)*16) = *(const uint4*)uu;
}

// ====================== weight -> int8 digit planes (swizzled) ==============
// planes: [oblk][s(I/64)][p(5)][lane(64)][16 B] -- MFMA A-frag register order:
// lane = quad*16+col holds digits of w[oblk*16+col][s*64 + quad*16 + 0..15].
__global__ __launch_bounds__(256)
void decompose_i8(const float* __restrict__ w, signed char* __restrict__ planes,
                  int I, int total)
{
    const int f = blockIdx.x * 256 + threadIdx.x;
    if (f >= total) return;
    const int NS = I / 64;
    const int per_oblk = NS * 5120;
    int rem  = f;
    const int oblk = rem / per_oblk;  rem -= oblk * per_oblk;
    const int s    = rem / 5120;      rem -= s * 5120;
    const int p    = rem >> 10;
    const int l    = (rem & 1023) >> 4;
    const int j    = rem & 15;
    const int quad = l >> 4, col = l & 15;
    const float wv = w[(size_t)(oblk*16 + col) * I + s*64 + quad*16 + j];
    long long v = llrint((double)wv * 274877906944.0);   // w * 2^38, exact int
    int d = 0;
    for (int q = 0; q <= p; ++q) {                       // balanced base-256
        d = (int)((v + 128) & 255) - 128;
        v = (v - d) >> 8;
    }
    planes[f] = (signed char)d;
}

// ============================ gemm-only kernel ==============================
// grid (B, O/16): b fastest (A-planes L2-hot). Two-pass acc[5][2] i8 MFMA
// over all 256 t -> exact fp64 recombine -> LDS transpose -> coalesced a
// store. No conv phase: live set ~90 VGPR; capped 128 -> 4 waves/SIMD.
template<int I>
__global__ __launch_bounds__(256) __attribute__((amdgpu_num_vgpr(128)))
void gemm_i8(const signed char* __restrict__ bexp,    // [b][I/16][256][16]
             const signed char* __restrict__ planes,  // swizzled A planes
             double*            __restrict__ au,      // [B][256][OS] (a out)
             int OS)
{
    constexpr int NS = I / 64;
    __shared__ double a_lds[257 * 17];                   // padded (row 256 unused)

    const int tid  = threadIdx.x;
    const int lane = tid & 63;
    const int wvu  = tid >> 6;
    const int quad = lane >> 4;
    const int col  = lane & 15;
    const int b    = blockIdx.x;
    const int oblk = blockIdx.y;
    const int o0   = oblk * 16;
    const int tw   = wvu * 64;

    const signed char* Apg = planes + (size_t)oblk * NS * 5120 + lane * 16;
    const double inv = 1.0 / 274877906944.0;             // 2^-38

    #pragma unroll 1
    for (int half = 0; half < 2; ++half) {
        const signed char* Bx = bexp +
            (((size_t)b*(I/16) + quad)*256 + tw + half*32 + col)*16;

        v4i acc[5][2];
        #pragma unroll
        for (int p = 0; p < 5; ++p)
            #pragma unroll
            for (int nt = 0; nt < 2; ++nt)
                acc[p][nt] = (v4i){0, 0, 0, 0};

        #pragma unroll 1
        for (int s = 0; s < NS; ++s) {
            v4i af[5];
            #pragma unroll
            for (int p = 0; p < 5; ++p)
                af[p] = *(const v4i*)(const void*)(Apg + (size_t)s * 5120 + p * 1024);
            v4i bf[2];
            #pragma unroll
            for (int nt = 0; nt < 2; ++nt)
                bf[nt] = *(const v4i*)(const void*)(Bx + (size_t)s * 16384 + nt * 256);

            #pragma unroll
            for (int nt = 0; nt < 2; ++nt)
                #pragma unroll
                for (int p = 0; p < 5; ++p)
                    acc[p][nt] = __builtin_amdgcn_mfma_i32_16x16x64_i8(
                                     af[p], bf[nt], acc[p][nt], 0, 0, 0);
        }

        // recombine: exact fp64 a into LDS (verified mapping)
        #pragma unroll
        for (int nt = 0; nt < 2; ++nt) {
            const int t = tw + half*32 + nt*16 + col;
            #pragma unroll
            for (int r = 0; r < 4; ++r) {
                double v =            (double)acc[4][nt][r];
                v = v * 256.0 + (double)acc[3][nt][r];
                v = v * 256.0 + (double)acc[2][nt][r];
                v = v * 256.0 + (double)acc[1][nt][r];
                v = v * 256.0 + (double)acc[0][nt][r];
                a_lds[t * 17 + quad*4 + r] = v * inv;
            }
        }
    }
    __syncthreads();

    // coalesced a store: 16 lanes x 8 B = 128 B contiguous per t-row
    for (int e = tid; e < 4096; e += 256) {
        const int row = e >> 4, oo = e & 15;
        au[((size_t)b * 256 + row) * OS + o0 + oo] = a_lds[row * 17 + oo];
    }
}

// ======================= conv kernel (in-place on au) =======================
// grid (B, O/16). Loads its [256 t][16 o] a-tile fully into LDS (barrier),
// runs the verified 61-tap FIR, stores u over the same addresses. Each block
// owns its slice exclusively -> in-place is race-free. 35 KB LDS ->
// 4 blocks/CU; VGPR capped 128 (live ~60, slack) -> 4 waves/SIMD.
__global__ __launch_bounds__(256) __attribute__((amdgpu_num_vgpr(128)))
void conv_fir(double* au, int OS)
{
    __shared__ double a_lds[257 * 17];                   // 34.95 KB (row 256 = 0)
    __shared__ double srmE[68];

    const int tid  = threadIdx.x;
    const int b    = blockIdx.x;
    const int oblk = blockIdx.y;
    const int o0   = oblk * 16;

    if (tid < 68) {
        const int k = tid - 2;
        double v = 0.0;
        if (k >= 1 && k <= 61) {
            double wv = (double)k / 8.0 * exp(1.0 - (double)k / 8.0);
            v = (double)(float)wv;     // fp32-rounded tap, widened (R1-R18)
        }
        srmE[tid] = v;
    }

    // full tile load (coalesced: 16 lanes x 8 B = 128 B per t-row)
    for (int e = tid; e < 4096; e += 256) {
        const int row = e >> 4, oo = e & 15;
        a_lds[row * 17 + oo] = au[((size_t)b * 256 + row) * OS + o0 + oo];
    }
    if (tid < 17) a_lds[256 * 17 + tid] = 0.0;           // zero-guard row
    __syncthreads();

    // ---------------- conv: 61-tap FIR from LDS (verified) ------------------
    const int o    = tid & 15;
    const int tgrp = tid >> 4;                           // 0..15
    #pragma unroll
    for (int pass = 0; pass < 4; ++pass) {
        const int T0b = pass * 64 + tgrp * 4;
        double u0 = 0, u1 = 0, u2 = 0, u3 = 0;
        double w1 = srmE[64], w2 = srmE[65], w3 = srmE[66];   // zero pads
        for (int d = 0; d < 64; d += 4) {
            const int row = T0b - 61 + d;
            const int r0 = (row + 0 < 0) ? 256 : row + 0;
            const int r1 = (row + 1 < 0) ? 256 : row + 1;
            const int r2 = (row + 2 < 0) ? 256 : row + 2;
            const int r3 = (row + 3 < 0) ? 256 : row + 3;
            const double av0 = a_lds[r0 * 17 + o];
            const double av1 = a_lds[r1 * 17 + o];
            const double av2 = a_lds[r2 * 17 + o];
            const double av3 = a_lds[r3 * 17 + o];
            const double n0 = srmE[63 - d], n1 = srmE[62 - d];
            const double n2 = srmE[61 - d], n3 = srmE[60 - d];
            u0 = fma(n0, av0, u0); u1 = fma(w1, av0, u1); u2 = fma(w2, av0, u2); u3 = fma(w3, av0, u3);
            u0 = fma(n1, av1, u0); u1 = fma(n0, av1, u1); u2 = fma(w1, av1, u2); u3 = fma(w2, av1, u3);
            u0 = fma(n2, av2, u0); u1 = fma(n1, av2, u1); u2 = fma(n0, av2, u2); u3 = fma(w1, av2, u3);
            u0 = fma(n3, av3, u0); u1 = fma(n2, av3, u1); u2 = fma(n1, av3, u2); u3 = fma(n0, av3, u3);
            w1 = n3; w2 = n2; w3 = n1;
        }
        double* up = au + ((size_t)b * 256 + T0b) * OS + o0 + o;
        up[0]              = u0;
        up[(size_t)OS]     = u1;
        up[(size_t)OS * 2] = u2;
        up[(size_t)OS * 3] = u3;
    }
}

// ========================== scan (R8/R10-verified core) =====================
// lane = neuron; 256 sequential steps; refractory via 61-bit history mask.
// FINAL=false: ballots -> expanded i8 B-matrix bexp_out[b][g][t][m].
// FINAL=true:  f32 out[b][o][t].
template<bool FINAL>
__global__ __launch_bounds__(256)
void scan_spikes(const double* __restrict__ u, signed char* __restrict__ bexp_out,
                 float* __restrict__ f32_out, int OS)
{
    __shared__ double   ref64[KLEN];
    __shared__ uint32_t blds[8][256];   // 8 KB ballot staging
    const int tid = threadIdx.x;
    if (tid < KLEN) {
        double v = (double)tid / 8.0 * exp(1.0 - (double)tid / 8.0);
        ref64[tid] = (double)(float)(-20.0 * v);
    }
    __syncthreads();

    const int b     = blockIdx.y;
    const int obase = blockIdx.x * 256;
    const int o     = obase + tid;
    const int lane  = tid & 63;
    const int wv    = tid >> 6;
    const double* up = u + (size_t)b * TT * OS + o;

    uint64_t mask = 0;
    double cur0 = up[0], cur1 = up[OS], cur2 = up[2 * (size_t)OS], cur3 = up[3 * (size_t)OS];
    for (int t0 = 0; t0 < TT; t0 += 4) {
        double nx0 = 0, nx1 = 0, nx2 = 0, nx3 = 0;
        if (t0 + 4 < TT) {
            const double* pp = up + (size_t)(t0 + 4) * OS;
            nx0 = pp[0]; nx1 = pp[OS]; nx2 = pp[2 * (size_t)OS]; nx3 = pp[3 * (size_t)OS];
        }
        #pragma unroll
        for (int q = 0; q < 4; ++q) {
            const double uv = (q == 0) ? cur0 : (q == 1) ? cur1 : (q == 2) ? cur2 : cur3;
            uint64_t m = mask;
            double r0 = 0.0, r1 = 0.0;
            while (m) {
                int p = __builtin_ctzll(m); m &= m - 1;
                r0 += ref64[p + 1];
                if (m) { int pq = __builtin_ctzll(m); m &= m - 1; r1 += ref64[pq + 1]; }
            }
            const bool s = (uv + (r0 + r1)) >= THETA;
            const uint64_t bal = __ballot(s);
            if (lane == 0) {
                blds[wv * 2 + 0][t0 + q] = (uint32_t)bal;
                blds[wv * 2 + 1][t0 + q] = (uint32_t)(bal >> 32);
            }
            mask = ((mask << 1) | (s ? 1ull : 0ull)) & ((1ull << 61) - 1ull);
        }
        cur0 = nx0; cur1 = nx1; cur2 = nx2; cur3 = nx3;
    }
    __syncthreads();

    if (!FINAL) {
        // expand ballots to i8 B-matrix: entry g = obase/16 + gl, byte m =
        // bit ((gl&1)*16 + m) of word blds[gl>>1][t]  (i = g*16 + m)
        const int gbase = obase >> 4;
        for (int e = tid; e < 16 * 256; e += 256) {
            const int gl = e >> 8, t = e & 255;
            const uint32_t w = blds[gl >> 1][t];
            const uint32_t h = (w >> ((gl & 1) * 16)) & 0xFFFFu;
            uint32_t uu[4];
            #pragma unroll
            for (int j = 0; j < 4; ++j)
                uu[j] = (((h >> (4*j)) & 0xFu) * 0x00204081u) & 0x01010101u;
            *(uint4*)(bexp_out + (((size_t)b*128 + gbase + gl)*256 + t)*16) =
                *(const uint4*)uu;
        }
    } else {
        for (int ol = 0; ol < 256; ++ol) {
            const uint32_t w = blds[ol >> 5][tid];
            f32_out[((size_t)b * 512 + obase + ol) * TT + tid] =
                (float)((w >> (ol & 31)) & 1u);
        }
    }
}

// ================================ launcher ==================================
extern "C" void kernel_launch(void* const* d_in, const int* in_sizes, int n_in,
                              void* d_out, int out_size, void* d_ws, size_t ws_size,
                              hipStream_t stream)
{
    const float* x  = (const float*)d_in[0];   // [32][1024][256]
    const float* w1 = (const float*)d_in[1];   // [2048][1024]
    const float* w2 = (const float*)d_in[2];   // [512][2048]
    float* out = (float*)d_out;                // [32][512][256]

    char* ws = (char*)d_ws;
    // liveness-based layout (Bexp2 aliases dead P1/Bexp1): total ~158 MB
    signed char* P2    = (signed char*)ws;                      // 5.25 MB
    size_t roff = (size_t)32 * 32 * 5120;                       // 5242880
    signed char* P1    = (signed char*)(ws + roff);             // 10.5 MB
    signed char* Bexp1 = (signed char*)(ws + roff + (size_t)128*16*5120); // 8 MB
    signed char* Bexp2 = (signed char*)(ws + roff);             // 16 MB (alias)
    size_t uoff = roff + (size_t)128*16*5120 + (size_t)32*64*256*16; // 24117248
    double* au = (double*)(ws + uoff);          // 134 MB: a, then u in place

    expand_x<<<dim3(32, 64), 256, 0, stream>>>(x, Bexp1);
    decompose_i8<<<dim3((10485760 + 255)/256), 256, 0, stream>>>(w1, P1, 1024, 10485760);
    decompose_i8<<<dim3((5242880  + 255)/256), 256, 0, stream>>>(w2, P2, 2048, 5242880);

    // layer 1: 1024 -> 2048
    gemm_i8<1024><<<dim3(32, 128), 256, 0, stream>>>(Bexp1, P1, au, 2048);
    conv_fir<<<dim3(32, 128), 256, 0, stream>>>(au, 2048);
    scan_spikes<false><<<dim3(8, 32), 256, 0, stream>>>(au, Bexp2, nullptr, 2048);
    // layer 2: 2048 -> 512
    gemm_i8<2048><<<dim3(32, 32), 256, 0, stream>>>(Bexp2, P2, au, 512);
    conv_fir<<<dim3(32, 32), 256, 0, stream>>>(au, 512);
    scan_spikes<true><<<dim3(2, 32), 256, 0, stream>>>(au, nullptr, out, 512);
}

// Round 8
// 595.894 us; speedup vs baseline: 1.9271x; 1.9271x over previous
//
#include <hip/hip_runtime.h>
#include <math.h>
#include <stdint.h>

// SLAYER 2-layer SNN. Round 20: serialize conv passes under the 128 cap.
//   expand_x -> decompose_i8 x2 ->
//   gemm<1024> -> conv_fir -> scan<BITS->Bexp2> ->
//   gemm<2048> -> conv_fir -> scan<F32>.
// R19 post-mortem: conv at 128 spilled (WRITE 1.21 GB) because #pragma
// unroll expanded all 4 FIR passes -> scheduler interleaves 16 fp64 acc +
// 4x streams = ~150+ live > 128 -> loop-carried spills. Same failure as
// R15's gemm; same cure as R18's gemm: SERIALIZE first (pass-loop
// unroll 1 -> live ~50-60), THEN cap into slack. Per-SIMD chain count is
// preserved: 4 chains/wave x 4 waves = 16 (was 16 chains x 2 waves via
// registers). LDS traffic unchanged.
// Gate: conv WRITE_SIZE exactly 131072 KB / FETCH ~65 MB, else this line
// is dead and next round restructures conv (t-major thread mapping).
// Numerics byte-identical (absmax 0.0): pragma only, within-pass FIR
// accumulation order untouched.

#define TT     256
#define KLEN   62
#define THETA  10.0

typedef int v4i __attribute__((ext_vector_type(4)));

// ===================== expand x -> i8 B-matrix (layer 1) ====================
// x: [32][1024][256] f32 {0,1}; bexp: [b][g=i/16][t][m=i%16] i8 {0,1}
__global__ __launch_bounds__(256)
void expand_x(const float* __restrict__ x, signed char* __restrict__ bexp)
{
    const int b = blockIdx.x;
    const int g = blockIdx.y;             // 64 groups of 16 inputs
    const int t = threadIdx.x;
    const float* xp = x + ((size_t)b*1024 + g*16)*TT + t;
    uint32_t uu[4];
    #pragma unroll
    for (int j = 0; j < 4; ++j) {
        uint32_t w = 0;
        #pragma unroll
        for (int m = 0; m < 4; ++m)
            w |= (xp[(size_t)(j*4 + m)*TT] >= 0.5f) ? (1u << (8*m)) : 0u;
        uu[j] = w;
    }
    *(uint4*)(bexp + (((size_t)b*64 + g)*256 + t)*16) = *(const uint4*)uu;
}

// ====================== weight -> int8 digit planes (swizzled) ==============
// planes: [oblk][s(I/64)][p(5)][lane(64)][16 B] -- MFMA A-frag register order:
// lane = quad*16+col holds digits of w[oblk*16+col][s*64 + quad*16 + 0..15].
__global__ __launch_bounds__(256)
void decompose_i8(const float* __restrict__ w, signed char* __restrict__ planes,
                  int I, int total)
{
    const int f = blockIdx.x * 256 + threadIdx.x;
    if (f >= total) return;
    const int NS = I / 64;
    const int per_oblk = NS * 5120;
    int rem  = f;
    const int oblk = rem / per_oblk;  rem -= oblk * per_oblk;
    const int s    = rem / 5120;      rem -= s * 5120;
    const int p    = rem >> 10;
    const int l    = (rem & 1023) >> 4;
    const int j    = rem & 15;
    const int quad = l >> 4, col = l & 15;
    const float wv = w[(size_t)(oblk*16 + col) * I + s*64 + quad*16 + j];
    long long v = llrint((double)wv * 274877906944.0);   // w * 2^38, exact int
    int d = 0;
    for (int q = 0; q <= p; ++q) {                       // balanced base-256
        d = (int)((v + 128) & 255) - 128;
        v = (v - d) >> 8;
    }
    planes[f] = (signed char)d;
}

// ============================ gemm-only kernel ==============================
// grid (B, O/16): b fastest (A-planes L2-hot). Two-pass acc[5][2] i8 MFMA
// over all 256 t -> exact fp64 recombine -> LDS transpose -> coalesced a
// store. No conv phase: live set ~90 VGPR; capped 128 -> 4 waves/SIMD.
template<int I>
__global__ __launch_bounds__(256) __attribute__((amdgpu_num_vgpr(128)))
void gemm_i8(const signed char* __restrict__ bexp,    // [b][I/16][256][16]
             const signed char* __restrict__ planes,  // swizzled A planes
             double*            __restrict__ au,      // [B][256][OS] (a out)
             int OS)
{
    constexpr int NS = I / 64;
    __shared__ double a_lds[257 * 17];                   // padded (row 256 unused)

    const int tid  = threadIdx.x;
    const int lane = tid & 63;
    const int wvu  = tid >> 6;
    const int quad = lane >> 4;
    const int col  = lane & 15;
    const int b    = blockIdx.x;
    const int oblk = blockIdx.y;
    const int o0   = oblk * 16;
    const int tw   = wvu * 64;

    const signed char* Apg = planes + (size_t)oblk * NS * 5120 + lane * 16;
    const double inv = 1.0 / 274877906944.0;             // 2^-38

    #pragma unroll 1
    for (int half = 0; half < 2; ++half) {
        const signed char* Bx = bexp +
            (((size_t)b*(I/16) + quad)*256 + tw + half*32 + col)*16;

        v4i acc[5][2];
        #pragma unroll
        for (int p = 0; p < 5; ++p)
            #pragma unroll
            for (int nt = 0; nt < 2; ++nt)
                acc[p][nt] = (v4i){0, 0, 0, 0};

        #pragma unroll 1
        for (int s = 0; s < NS; ++s) {
            v4i af[5];
            #pragma unroll
            for (int p = 0; p < 5; ++p)
                af[p] = *(const v4i*)(const void*)(Apg + (size_t)s * 5120 + p * 1024);
            v4i bf[2];
            #pragma unroll
            for (int nt = 0; nt < 2; ++nt)
                bf[nt] = *(const v4i*)(const void*)(Bx + (size_t)s * 16384 + nt * 256);

            #pragma unroll
            for (int nt = 0; nt < 2; ++nt)
                #pragma unroll
                for (int p = 0; p < 5; ++p)
                    acc[p][nt] = __builtin_amdgcn_mfma_i32_16x16x64_i8(
                                     af[p], bf[nt], acc[p][nt], 0, 0, 0);
        }

        // recombine: exact fp64 a into LDS (verified mapping)
        #pragma unroll
        for (int nt = 0; nt < 2; ++nt) {
            const int t = tw + half*32 + nt*16 + col;
            #pragma unroll
            for (int r = 0; r < 4; ++r) {
                double v =            (double)acc[4][nt][r];
                v = v * 256.0 + (double)acc[3][nt][r];
                v = v * 256.0 + (double)acc[2][nt][r];
                v = v * 256.0 + (double)acc[1][nt][r];
                v = v * 256.0 + (double)acc[0][nt][r];
                a_lds[t * 17 + quad*4 + r] = v * inv;
            }
        }
    }
    __syncthreads();

    // coalesced a store: 16 lanes x 8 B = 128 B contiguous per t-row
    for (int e = tid; e < 4096; e += 256) {
        const int row = e >> 4, oo = e & 15;
        au[((size_t)b * 256 + row) * OS + o0 + oo] = a_lds[row * 17 + oo];
    }
}

// ======================= conv kernel (in-place on au) =======================
// grid (B, O/16). Loads its [256 t][16 o] a-tile fully into LDS (barrier),
// runs the verified 61-tap FIR, stores u over the same addresses. Each block
// owns its slice exclusively -> in-place is race-free. 35 KB LDS ->
// 4 blocks/CU; passes SERIALIZED (live ~50-60) under the 128 cap ->
// 4 waves/SIMD; 4 chains/wave x 4 waves = 16 fp64 chains per SIMD.
__global__ __launch_bounds__(256) __attribute__((amdgpu_num_vgpr(128)))
void conv_fir(double* au, int OS)
{
    __shared__ double a_lds[257 * 17];                   // 34.95 KB (row 256 = 0)
    __shared__ double srmE[68];

    const int tid  = threadIdx.x;
    const int b    = blockIdx.x;
    const int oblk = blockIdx.y;
    const int o0   = oblk * 16;

    if (tid < 68) {
        const int k = tid - 2;
        double v = 0.0;
        if (k >= 1 && k <= 61) {
            double wv = (double)k / 8.0 * exp(1.0 - (double)k / 8.0);
            v = (double)(float)wv;     // fp32-rounded tap, widened (R1-R19)
        }
        srmE[tid] = v;
    }

    // full tile load (coalesced: 16 lanes x 8 B = 128 B per t-row)
    for (int e = tid; e < 4096; e += 256) {
        const int row = e >> 4, oo = e & 15;
        a_lds[row * 17 + oo] = au[((size_t)b * 256 + row) * OS + o0 + oo];
    }
    if (tid < 17) a_lds[256 * 17 + tid] = 0.0;           // zero-guard row
    __syncthreads();

    // ---------------- conv: 61-tap FIR from LDS (verified) ------------------
    const int o    = tid & 15;
    const int tgrp = tid >> 4;                           // 0..15
    #pragma unroll 1
    for (int pass = 0; pass < 4; ++pass) {
        const int T0b = pass * 64 + tgrp * 4;
        double u0 = 0, u1 = 0, u2 = 0, u3 = 0;
        double w1 = srmE[64], w2 = srmE[65], w3 = srmE[66];   // zero pads
        for (int d = 0; d < 64; d += 4) {
            const int row = T0b - 61 + d;
            const int r0 = (row + 0 < 0) ? 256 : row + 0;
            const int r1 = (row + 1 < 0) ? 256 : row + 1;
            const int r2 = (row + 2 < 0) ? 256 : row + 2;
            const int r3 = (row + 3 < 0) ? 256 : row + 3;
            const double av0 = a_lds[r0 * 17 + o];
            const double av1 = a_lds[r1 * 17 + o];
            const double av2 = a_lds[r2 * 17 + o];
            const double av3 = a_lds[r3 * 17 + o];
            const double n0 = srmE[63 - d], n1 = srmE[62 - d];
            const double n2 = srmE[61 - d], n3 = srmE[60 - d];
            u0 = fma(n0, av0, u0); u1 = fma(w1, av0, u1); u2 = fma(w2, av0, u2); u3 = fma(w3, av0, u3);
            u0 = fma(n1, av1, u0); u1 = fma(n0, av1, u1); u2 = fma(w1, av1, u2); u3 = fma(w2, av1, u3);
            u0 = fma(n2, av2, u0); u1 = fma(n1, av2, u1); u2 = fma(n0, av2, u2); u3 = fma(w1, av2, u3);
            u0 = fma(n3, av3, u0); u1 = fma(n2, av3, u1); u2 = fma(n1, av3, u2); u3 = fma(n0, av3, u3);
            w1 = n3; w2 = n2; w3 = n1;
        }
        double* up = au + ((size_t)b * 256 + T0b) * OS + o0 + o;
        up[0]              = u0;
        up[(size_t)OS]     = u1;
        up[(size_t)OS * 2] = u2;
        up[(size_t)OS * 3] = u3;
    }
}

// ========================== scan (R8/R10-verified core) =====================
// lane = neuron; 256 sequential steps; refractory via 61-bit history mask.
// FINAL=false: ballots -> expanded i8 B-matrix bexp_out[b][g][t][m].
// FINAL=true:  f32 out[b][o][t].
template<bool FINAL>
__global__ __launch_bounds__(256)
void scan_spikes(const double* __restrict__ u, signed char* __restrict__ bexp_out,
                 float* __restrict__ f32_out, int OS)
{
    __shared__ double   ref64[KLEN];
    __shared__ uint32_t blds[8][256];   // 8 KB ballot staging
    const int tid = threadIdx.x;
    if (tid < KLEN) {
        double v = (double)tid / 8.0 * exp(1.0 - (double)tid / 8.0);
        ref64[tid] = (double)(float)(-20.0 * v);
    }
    __syncthreads();

    const int b     = blockIdx.y;
    const int obase = blockIdx.x * 256;
    const int o     = obase + tid;
    const int lane  = tid & 63;
    const int wv    = tid >> 6;
    const double* up = u + (size_t)b * TT * OS + o;

    uint64_t mask = 0;
    double cur0 = up[0], cur1 = up[OS], cur2 = up[2 * (size_t)OS], cur3 = up[3 * (size_t)OS];
    for (int t0 = 0; t0 < TT; t0 += 4) {
        double nx0 = 0, nx1 = 0, nx2 = 0, nx3 = 0;
        if (t0 + 4 < TT) {
            const double* pp = up + (size_t)(t0 + 4) * OS;
            nx0 = pp[0]; nx1 = pp[OS]; nx2 = pp[2 * (size_t)OS]; nx3 = pp[3 * (size_t)OS];
        }
        #pragma unroll
        for (int q = 0; q < 4; ++q) {
            const double uv = (q == 0) ? cur0 : (q == 1) ? cur1 : (q == 2) ? cur2 : cur3;
            uint64_t m = mask;
            double r0 = 0.0, r1 = 0.0;
            while (m) {
                int p = __builtin_ctzll(m); m &= m - 1;
                r0 += ref64[p + 1];
                if (m) { int pq = __builtin_ctzll(m); m &= m - 1; r1 += ref64[pq + 1]; }
            }
            const bool s = (uv + (r0 + r1)) >= THETA;
            const uint64_t bal = __ballot(s);
            if (lane == 0) {
                blds[wv * 2 + 0][t0 + q] = (uint32_t)bal;
                blds[wv * 2 + 1][t0 + q] = (uint32_t)(bal >> 32);
            }
            mask = ((mask << 1) | (s ? 1ull : 0ull)) & ((1ull << 61) - 1ull);
        }
        cur0 = nx0; cur1 = nx1; cur2 = nx2; cur3 = nx3;
    }
    __syncthreads();

    if (!FINAL) {
        // expand ballots to i8 B-matrix: entry g = obase/16 + gl, byte m =
        // bit ((gl&1)*16 + m) of word blds[gl>>1][t]  (i = g*16 + m)
        const int gbase = obase >> 4;
        for (int e = tid; e < 16 * 256; e += 256) {
            const int gl = e >> 8, t = e & 255;
            const uint32_t w = blds[gl >> 1][t];
            const uint32_t h = (w >> ((gl & 1) * 16)) & 0xFFFFu;
            uint32_t uu[4];
            #pragma unroll
            for (int j = 0; j < 4; ++j)
                uu[j] = (((h >> (4*j)) & 0xFu) * 0x00204081u) & 0x01010101u;
            *(uint4*)(bexp_out + (((size_t)b*128 + gbase + gl)*256 + t)*16) =
                *(const uint4*)uu;
        }
    } else {
        for (int ol = 0; ol < 256; ++ol) {
            const uint32_t w = blds[ol >> 5][tid];
            f32_out[((size_t)b * 512 + obase + ol) * TT + tid] =
                (float)((w >> (ol & 31)) & 1u);
        }
    }
}

// ================================ launcher ==================================
extern "C" void kernel_launch(void* const* d_in, const int* in_sizes, int n_in,
                              void* d_out, int out_size, void* d_ws, size_t ws_size,
                              hipStream_t stream)
{
    const float* x  = (const float*)d_in[0];   // [32][1024][256]
    const float* w1 = (const float*)d_in[1];   // [2048][1024]
    const float* w2 = (const float*)d_in[2];   // [512][2048]
    float* out = (float*)d_out;                // [32][512][256]

    char* ws = (char*)d_ws;
    // liveness-based layout (Bexp2 aliases dead P1/Bexp1): total ~158 MB
    signed char* P2    = (signed char*)ws;                      // 5.25 MB
    size_t roff = (size_t)32 * 32 * 5120;                       // 5242880
    signed char* P1    = (signed char*)(ws + roff);             // 10.5 MB
    signed char* Bexp1 = (signed char*)(ws + roff + (size_t)128*16*5120); // 8 MB
    signed char* Bexp2 = (signed char*)(ws + roff);             // 16 MB (alias)
    size_t uoff = roff + (size_t)128*16*5120 + (size_t)32*64*256*16; // 24117248
    double* au = (double*)(ws + uoff);          // 134 MB: a, then u in place

    expand_x<<<dim3(32, 64), 256, 0, stream>>>(x, Bexp1);
    decompose_i8<<<dim3((10485760 + 255)/256), 256, 0, stream>>>(w1, P1, 1024, 10485760);
    decompose_i8<<<dim3((5242880  + 255)/256), 256, 0, stream>>>(w2, P2, 2048, 5242880);

    // layer 1: 1024 -> 2048
    gemm_i8<1024><<<dim3(32, 128), 256, 0, stream>>>(Bexp1, P1, au, 2048);
    conv_fir<<<dim3(32, 128), 256, 0, stream>>>(au, 2048);
    scan_spikes<false><<<dim3(8, 32), 256, 0, stream>>>(au, Bexp2, nullptr, 2048);
    // layer 2: 2048 -> 512
    gemm_i8<2048><<<dim3(32, 32), 256, 0, stream>>>(Bexp2, P2, au, 512);
    conv_fir<<<dim3(32, 32), 256, 0, stream>>>(au, 512);
    scan_spikes<true><<<dim3(2, 32), 256, 0, stream>>>(au, nullptr, out, 512);
}

// Round 9
// 593.076 us; speedup vs baseline: 1.9363x; 1.0048x over previous
//
#include <hip/hip_runtime.h>
#include <math.h>
#include <stdint.h>

// SLAYER 2-layer SNN. Round 21: K-loop unroll 2 inside the register slack.
//   expand_x -> decompose_i8 x2 ->
//   gemm<1024> -> conv_fir -> scan<BITS->Bexp2> ->
//   gemm<2048> -> conv_fir -> scan<F32>.
// R20 post-mortem: serialize+cap worked everywhere (595.9us total, best).
// gemm_i8 now leads at 130us: VGPR=52 (!), Occ 41% (= 4-blk/CU LDS cap),
// MfmaUtil 27, HBM 19%. Floor ~30us (11 MFMA + 21 a-write) -> gap is the
// serialized K-loop: unroll 1 blocks loads from crossing the back-edge, so
// each s-iter eats ~200cyc L2 latency that 4 waves/SIMD only half-hide.
// R21: s-loop unroll 2 -- ping-pong af/bf (+28 regs) under the 128 cap.
// Projected live ~116 < 128: prefetch ILP at unchanged occupancy. This is
// R12's prefetch on a body where it finally fits.
// Gate: gemm WRITE_SIZE exactly 131072 KB (spill detector); if it grows,
// revert to unroll 1 and attack conv/scan instead.
// Numerics byte-identical (absmax 0.0): per-chain MFMA order still s
// ascending; i32 accum exact; nothing else touched.

#define TT     256
#define KLEN   62
#define THETA  10.0

typedef int v4i __attribute__((ext_vector_type(4)));

// ===================== expand x -> i8 B-matrix (layer 1) ====================
// x: [32][1024][256] f32 {0,1}; bexp: [b][g=i/16][t][m=i%16] i8 {0,1}
__global__ __launch_bounds__(256)
void expand_x(const float* __restrict__ x, signed char* __restrict__ bexp)
{
    const int b = blockIdx.x;
    const int g = blockIdx.y;             // 64 groups of 16 inputs
    const int t = threadIdx.x;
    const float* xp = x + ((size_t)b*1024 + g*16)*TT + t;
    uint32_t uu[4];
    #pragma unroll
    for (int j = 0; j < 4; ++j) {
        uint32_t w = 0;
        #pragma unroll
        for (int m = 0; m < 4; ++m)
            w |= (xp[(size_t)(j*4 + m)*TT] >= 0.5f) ? (1u << (8*m)) : 0u;
        uu[j] = w;
    }
    *(uint4*)(bexp + (((size_t)b*64 + g)*256 + t)*16) = *(const uint4*)uu;
}

// ====================== weight -> int8 digit planes (swizzled) ==============
// planes: [oblk][s(I/64)][p(5)][lane(64)][16 B] -- MFMA A-frag register order:
// lane = quad*16+col holds digits of w[oblk*16+col][s*64 + quad*16 + 0..15].
__global__ __launch_bounds__(256)
void decompose_i8(const float* __restrict__ w, signed char* __restrict__ planes,
                  int I, int total)
{
    const int f = blockIdx.x * 256 + threadIdx.x;
    if (f >= total) return;
    const int NS = I / 64;
    const int per_oblk = NS * 5120;
    int rem  = f;
    const int oblk = rem / per_oblk;  rem -= oblk * per_oblk;
    const int s    = rem / 5120;      rem -= s * 5120;
    const int p    = rem >> 10;
    const int l    = (rem & 1023) >> 4;
    const int j    = rem & 15;
    const int quad = l >> 4, col = l & 15;
    const float wv = w[(size_t)(oblk*16 + col) * I + s*64 + quad*16 + j];
    long long v = llrint((double)wv * 274877906944.0);   // w * 2^38, exact int
    int d = 0;
    for (int q = 0; q <= p; ++q) {                       // balanced base-256
        d = (int)((v + 128) & 255) - 128;
        v = (v - d) >> 8;
    }
    planes[f] = (signed char)d;
}

// ============================ gemm-only kernel ==============================
// grid (B, O/16): b fastest (A-planes L2-hot). Two-pass acc[5][2] i8 MFMA,
// s-loop unroll 2 (ping-pong prefetch, live ~116 < 128 cap) -> exact fp64
// recombine -> LDS transpose -> coalesced a store. 4 waves/SIMD.
template<int I>
__global__ __launch_bounds__(256) __attribute__((amdgpu_num_vgpr(128)))
void gemm_i8(const signed char* __restrict__ bexp,    // [b][I/16][256][16]
             const signed char* __restrict__ planes,  // swizzled A planes
             double*            __restrict__ au,      // [B][256][OS] (a out)
             int OS)
{
    constexpr int NS = I / 64;
    __shared__ double a_lds[257 * 17];                   // padded (row 256 unused)

    const int tid  = threadIdx.x;
    const int lane = tid & 63;
    const int wvu  = tid >> 6;
    const int quad = lane >> 4;
    const int col  = lane & 15;
    const int b    = blockIdx.x;
    const int oblk = blockIdx.y;
    const int o0   = oblk * 16;
    const int tw   = wvu * 64;

    const signed char* Apg = planes + (size_t)oblk * NS * 5120 + lane * 16;
    const double inv = 1.0 / 274877906944.0;             // 2^-38

    #pragma unroll 1
    for (int half = 0; half < 2; ++half) {
        const signed char* Bx = bexp +
            (((size_t)b*(I/16) + quad)*256 + tw + half*32 + col)*16;

        v4i acc[5][2];
        #pragma unroll
        for (int p = 0; p < 5; ++p)
            #pragma unroll
            for (int nt = 0; nt < 2; ++nt)
                acc[p][nt] = (v4i){0, 0, 0, 0};

        #pragma unroll 2
        for (int s = 0; s < NS; ++s) {
            v4i af[5];
            #pragma unroll
            for (int p = 0; p < 5; ++p)
                af[p] = *(const v4i*)(const void*)(Apg + (size_t)s * 5120 + p * 1024);
            v4i bf[2];
            #pragma unroll
            for (int nt = 0; nt < 2; ++nt)
                bf[nt] = *(const v4i*)(const void*)(Bx + (size_t)s * 16384 + nt * 256);

            #pragma unroll
            for (int nt = 0; nt < 2; ++nt)
                #pragma unroll
                for (int p = 0; p < 5; ++p)
                    acc[p][nt] = __builtin_amdgcn_mfma_i32_16x16x64_i8(
                                     af[p], bf[nt], acc[p][nt], 0, 0, 0);
        }

        // recombine: exact fp64 a into LDS (verified mapping)
        #pragma unroll
        for (int nt = 0; nt < 2; ++nt) {
            const int t = tw + half*32 + nt*16 + col;
            #pragma unroll
            for (int r = 0; r < 4; ++r) {
                double v =            (double)acc[4][nt][r];
                v = v * 256.0 + (double)acc[3][nt][r];
                v = v * 256.0 + (double)acc[2][nt][r];
                v = v * 256.0 + (double)acc[1][nt][r];
                v = v * 256.0 + (double)acc[0][nt][r];
                a_lds[t * 17 + quad*4 + r] = v * inv;
            }
        }
    }
    __syncthreads();

    // coalesced a store: 16 lanes x 8 B = 128 B contiguous per t-row
    for (int e = tid; e < 4096; e += 256) {
        const int row = e >> 4, oo = e & 15;
        au[((size_t)b * 256 + row) * OS + o0 + oo] = a_lds[row * 17 + oo];
    }
}

// ======================= conv kernel (in-place on au) =======================
// grid (B, O/16). Loads its [256 t][16 o] a-tile fully into LDS (barrier),
// runs the verified 61-tap FIR, stores u over the same addresses. Each block
// owns its slice exclusively -> in-place is race-free. 35 KB LDS ->
// 4 blocks/CU; passes SERIALIZED (live ~50-60) under the 128 cap ->
// 4 waves/SIMD; 4 chains/wave x 4 waves = 16 fp64 chains per SIMD.
__global__ __launch_bounds__(256) __attribute__((amdgpu_num_vgpr(128)))
void conv_fir(double* au, int OS)
{
    __shared__ double a_lds[257 * 17];                   // 34.95 KB (row 256 = 0)
    __shared__ double srmE[68];

    const int tid  = threadIdx.x;
    const int b    = blockIdx.x;
    const int oblk = blockIdx.y;
    const int o0   = oblk * 16;

    if (tid < 68) {
        const int k = tid - 2;
        double v = 0.0;
        if (k >= 1 && k <= 61) {
            double wv = (double)k / 8.0 * exp(1.0 - (double)k / 8.0);
            v = (double)(float)wv;     // fp32-rounded tap, widened (R1-R20)
        }
        srmE[tid] = v;
    }

    // full tile load (coalesced: 16 lanes x 8 B = 128 B per t-row)
    for (int e = tid; e < 4096; e += 256) {
        const int row = e >> 4, oo = e & 15;
        a_lds[row * 17 + oo] = au[((size_t)b * 256 + row) * OS + o0 + oo];
    }
    if (tid < 17) a_lds[256 * 17 + tid] = 0.0;           // zero-guard row
    __syncthreads();

    // ---------------- conv: 61-tap FIR from LDS (verified) ------------------
    const int o    = tid & 15;
    const int tgrp = tid >> 4;                           // 0..15
    #pragma unroll 1
    for (int pass = 0; pass < 4; ++pass) {
        const int T0b = pass * 64 + tgrp * 4;
        double u0 = 0, u1 = 0, u2 = 0, u3 = 0;
        double w1 = srmE[64], w2 = srmE[65], w3 = srmE[66];   // zero pads
        for (int d = 0; d < 64; d += 4) {
            const int row = T0b - 61 + d;
            const int r0 = (row + 0 < 0) ? 256 : row + 0;
            const int r1 = (row + 1 < 0) ? 256 : row + 1;
            const int r2 = (row + 2 < 0) ? 256 : row + 2;
            const int r3 = (row + 3 < 0) ? 256 : row + 3;
            const double av0 = a_lds[r0 * 17 + o];
            const double av1 = a_lds[r1 * 17 + o];
            const double av2 = a_lds[r2 * 17 + o];
            const double av3 = a_lds[r3 * 17 + o];
            const double n0 = srmE[63 - d], n1 = srmE[62 - d];
            const double n2 = srmE[61 - d], n3 = srmE[60 - d];
            u0 = fma(n0, av0, u0); u1 = fma(w1, av0, u1); u2 = fma(w2, av0, u2); u3 = fma(w3, av0, u3);
            u0 = fma(n1, av1, u0); u1 = fma(n0, av1, u1); u2 = fma(w1, av1, u2); u3 = fma(w2, av1, u3);
            u0 = fma(n2, av2, u0); u1 = fma(n1, av2, u1); u2 = fma(n0, av2, u2); u3 = fma(w1, av2, u3);
            u0 = fma(n3, av3, u0); u1 = fma(n2, av3, u1); u2 = fma(n1, av3, u2); u3 = fma(n0, av3, u3);
            w1 = n3; w2 = n2; w3 = n1;
        }
        double* up = au + ((size_t)b * 256 + T0b) * OS + o0 + o;
        up[0]              = u0;
        up[(size_t)OS]     = u1;
        up[(size_t)OS * 2] = u2;
        up[(size_t)OS * 3] = u3;
    }
}

// ========================== scan (R8/R10-verified core) =====================
// lane = neuron; 256 sequential steps; refractory via 61-bit history mask.
// FINAL=false: ballots -> expanded i8 B-matrix bexp_out[b][g][t][m].
// FINAL=true:  f32 out[b][o][t].
template<bool FINAL>
__global__ __launch_bounds__(256)
void scan_spikes(const double* __restrict__ u, signed char* __restrict__ bexp_out,
                 float* __restrict__ f32_out, int OS)
{
    __shared__ double   ref64[KLEN];
    __shared__ uint32_t blds[8][256];   // 8 KB ballot staging
    const int tid = threadIdx.x;
    if (tid < KLEN) {
        double v = (double)tid / 8.0 * exp(1.0 - (double)tid / 8.0);
        ref64[tid] = (double)(float)(-20.0 * v);
    }
    __syncthreads();

    const int b     = blockIdx.y;
    const int obase = blockIdx.x * 256;
    const int o     = obase + tid;
    const int lane  = tid & 63;
    const int wv    = tid >> 6;
    const double* up = u + (size_t)b * TT * OS + o;

    uint64_t mask = 0;
    double cur0 = up[0], cur1 = up[OS], cur2 = up[2 * (size_t)OS], cur3 = up[3 * (size_t)OS];
    for (int t0 = 0; t0 < TT; t0 += 4) {
        double nx0 = 0, nx1 = 0, nx2 = 0, nx3 = 0;
        if (t0 + 4 < TT) {
            const double* pp = up + (size_t)(t0 + 4) * OS;
            nx0 = pp[0]; nx1 = pp[OS]; nx2 = pp[2 * (size_t)OS]; nx3 = pp[3 * (size_t)OS];
        }
        #pragma unroll
        for (int q = 0; q < 4; ++q) {
            const double uv = (q == 0) ? cur0 : (q == 1) ? cur1 : (q == 2) ? cur2 : cur3;
            uint64_t m = mask;
            double r0 = 0.0, r1 = 0.0;
            while (m) {
                int p = __builtin_ctzll(m); m &= m - 1;
                r0 += ref64[p + 1];
                if (m) { int pq = __builtin_ctzll(m); m &= m - 1; r1 += ref64[pq + 1]; }
            }
            const bool s = (uv + (r0 + r1)) >= THETA;
            const uint64_t bal = __ballot(s);
            if (lane == 0) {
                blds[wv * 2 + 0][t0 + q] = (uint32_t)bal;
                blds[wv * 2 + 1][t0 + q] = (uint32_t)(bal >> 32);
            }
            mask = ((mask << 1) | (s ? 1ull : 0ull)) & ((1ull << 61) - 1ull);
        }
        cur0 = nx0; cur1 = nx1; cur2 = nx2; cur3 = nx3;
    }
    __syncthreads();

    if (!FINAL) {
        // expand ballots to i8 B-matrix: entry g = obase/16 + gl, byte m =
        // bit ((gl&1)*16 + m) of word blds[gl>>1][t]  (i = g*16 + m)
        const int gbase = obase >> 4;
        for (int e = tid; e < 16 * 256; e += 256) {
            const int gl = e >> 8, t = e & 255;
            const uint32_t w = blds[gl >> 1][t];
            const uint32_t h = (w >> ((gl & 1) * 16)) & 0xFFFFu;
            uint32_t uu[4];
            #pragma unroll
            for (int j = 0; j < 4; ++j)
                uu[j] = (((h >> (4*j)) & 0xFu) * 0x00204081u) & 0x01010101u;
            *(uint4*)(bexp_out + (((size_t)b*128 + gbase + gl)*256 + t)*16) =
                *(const uint4*)uu;
        }
    } else {
        for (int ol = 0; ol < 256; ++ol) {
            const uint32_t w = blds[ol >> 5][tid];
            f32_out[((size_t)b * 512 + obase + ol) * TT + tid] =
                (float)((w >> (ol & 31)) & 1u);
        }
    }
}

// ================================ launcher ==================================
extern "C" void kernel_launch(void* const* d_in, const int* in_sizes, int n_in,
                              void* d_out, int out_size, void* d_ws, size_t ws_size,
                              hipStream_t stream)
{
    const float* x  = (const float*)d_in[0];   // [32][1024][256]
    const float* w1 = (const float*)d_in[1];   // [2048][1024]
    const float* w2 = (const float*)d_in[2];   // [512][2048]
    float* out = (float*)d_out;                // [32][512][256]

    char* ws = (char*)d_ws;
    // liveness-based layout (Bexp2 aliases dead P1/Bexp1): total ~158 MB
    signed char* P2    = (signed char*)ws;                      // 5.25 MB
    size_t roff = (size_t)32 * 32 * 5120;                       // 5242880
    signed char* P1    = (signed char*)(ws + roff);             // 10.5 MB
    signed char* Bexp1 = (signed char*)(ws + roff + (size_t)128*16*5120); // 8 MB
    signed char* Bexp2 = (signed char*)(ws + roff);             // 16 MB (alias)
    size_t uoff = roff + (size_t)128*16*5120 + (size_t)32*64*256*16; // 24117248
    double* au = (double*)(ws + uoff);          // 134 MB: a, then u in place

    expand_x<<<dim3(32, 64), 256, 0, stream>>>(x, Bexp1);
    decompose_i8<<<dim3((10485760 + 255)/256), 256, 0, stream>>>(w1, P1, 1024, 10485760);
    decompose_i8<<<dim3((5242880  + 255)/256), 256, 0, stream>>>(w2, P2, 2048, 5242880);

    // layer 1: 1024 -> 2048
    gemm_i8<1024><<<dim3(32, 128), 256, 0, stream>>>(Bexp1, P1, au, 2048);
    conv_fir<<<dim3(32, 128), 256, 0, stream>>>(au, 2048);
    scan_spikes<false><<<dim3(8, 32), 256, 0, stream>>>(au, Bexp2, nullptr, 2048);
    // layer 2: 2048 -> 512
    gemm_i8<2048><<<dim3(32, 32), 256, 0, stream>>>(Bexp2, P2, au, 512);
    conv_fir<<<dim3(32, 32), 256, 0, stream>>>(au, 512);
    scan_spikes<true><<<dim3(2, 32), 256, 0, stream>>>(au, nullptr, out, 512);
}

// Round 10
// 574.083 us; speedup vs baseline: 2.0003x; 1.0331x over previous
//
#include <hip/hip_runtime.h>
#include <math.h>
#include <stdint.h>

// SLAYER 2-layer SNN. Round 22: re-fuse gemm+conv with all spill fixes.
//   expand_x -> decompose_i8 x2 ->
//   fused_gc<1024> -> scan<BITS->Bexp2> -> fused_gc<2048> -> scan<F32>.
// R21 post-mortem: s-loop unroll 2 was a no-op (VGPR stayed 52, dur 132us)
// -- compiler won't pipeline across the back-edge; split-gemm micro-tuning
// is dead. Synthesis instead: R15's fused spill at cap 128 is now fully
// explained -- R19 proved conv's UNROLLED pass loop alone needs >128
// (spilled standalone); R15 contained it. Every phase is since proven
// clean at the cap: gemm two-pass acc[5][2] + pre-expanded B = 52 VGPR
// (R18-R21); conv with pass unroll 1 fits (R20). R22: fuse them. conv
// reads a straight from the a_lds tile gemm deposits -> deletes the a
// store (134 MB) + a re-load (134 MB) per layer and two launches, keeps
// 4 waves/SIMD. Gate: fused WRITE_SIZE exactly 131072 KB (u only).
// Numerics byte-identical (absmax 0.0): phase bodies identical to split.

#define TT     256
#define KLEN   62
#define THETA  10.0

typedef int v4i __attribute__((ext_vector_type(4)));

// ===================== expand x -> i8 B-matrix (layer 1) ====================
// x: [32][1024][256] f32 {0,1}; bexp: [b][g=i/16][t][m=i%16] i8 {0,1}
__global__ __launch_bounds__(256)
void expand_x(const float* __restrict__ x, signed char* __restrict__ bexp)
{
    const int b = blockIdx.x;
    const int g = blockIdx.y;             // 64 groups of 16 inputs
    const int t = threadIdx.x;
    const float* xp = x + ((size_t)b*1024 + g*16)*TT + t;
    uint32_t uu[4];
    #pragma unroll
    for (int j = 0; j < 4; ++j) {
        uint32_t w = 0;
        #pragma unroll
        for (int m = 0; m < 4; ++m)
            w |= (xp[(size_t)(j*4 + m)*TT] >= 0.5f) ? (1u << (8*m)) : 0u;
        uu[j] = w;
    }
    *(uint4*)(bexp + (((size_t)b*64 + g)*256 + t)*16) = *(const uint4*)uu;
}

// ====================== weight -> int8 digit planes (swizzled) ==============
// planes: [oblk][s(I/64)][p(5)][lane(64)][16 B] -- MFMA A-frag register order:
// lane = quad*16+col holds digits of w[oblk*16+col][s*64 + quad*16 + 0..15].
__global__ __launch_bounds__(256)
void decompose_i8(const float* __restrict__ w, signed char* __restrict__ planes,
                  int I, int total)
{
    const int f = blockIdx.x * 256 + threadIdx.x;
    if (f >= total) return;
    const int NS = I / 64;
    const int per_oblk = NS * 5120;
    int rem  = f;
    const int oblk = rem / per_oblk;  rem -= oblk * per_oblk;
    const int s    = rem / 5120;      rem -= s * 5120;
    const int p    = rem >> 10;
    const int l    = (rem & 1023) >> 4;
    const int j    = rem & 15;
    const int quad = l >> 4, col = l & 15;
    const float wv = w[(size_t)(oblk*16 + col) * I + s*64 + quad*16 + j];
    long long v = llrint((double)wv * 274877906944.0);   // w * 2^38, exact int
    int d = 0;
    for (int q = 0; q <= p; ++q) {                       // balanced base-256
        d = (int)((v + 128) & 255) - 128;
        v = (v - d) >> 8;
    }
    planes[f] = (signed char)d;
}

// ====================== fused gemm+conv kernel ==============================
// grid (B, O/16): b fastest (A-planes L2-hot). Phase 1: two-pass acc[5][2]
// i8 MFMA (pre-expanded B, s-loop unroll 1 -- 52-VGPR body per R18-R21) ->
// exact fp64 recombine into a_lds. Barrier. Phase 2: verified 61-tap FIR
// from a_lds with pass-loop unroll 1 (fits per R20) -> u stores only.
// Phases are register-disjoint; max live ~90 < 128 cap -> 4 waves/SIMD.
template<int I>
__global__ __launch_bounds__(256) __attribute__((amdgpu_num_vgpr(128)))
void fused_gc(const signed char* __restrict__ bexp,    // [b][I/16][256][16]
              const signed char* __restrict__ planes,  // swizzled A planes
              double*            __restrict__ u,       // [B][256][OS]
              int OS)
{
    constexpr int NS = I / 64;
    __shared__ double a_lds[257 * 17];                   // 34.95 KB (row 256 = 0)
    __shared__ double srmE[68];

    const int tid  = threadIdx.x;
    const int lane = tid & 63;
    const int wvu  = tid >> 6;
    const int quad = lane >> 4;
    const int col  = lane & 15;
    const int b    = blockIdx.x;
    const int oblk = blockIdx.y;
    const int o0   = oblk * 16;
    const int tw   = wvu * 64;

    if (tid < 68) {
        const int k = tid - 2;
        double v = 0.0;
        if (k >= 1 && k <= 61) {
            double wv = (double)k / 8.0 * exp(1.0 - (double)k / 8.0);
            v = (double)(float)wv;     // fp32-rounded tap, widened (R1-R21)
        }
        srmE[tid] = v;
    }

    // ---------------- phase 1: gemm (split-proven 52-VGPR body) -------------
    const signed char* Apg = planes + (size_t)oblk * NS * 5120 + lane * 16;
    const double inv = 1.0 / 274877906944.0;             // 2^-38

    #pragma unroll 1
    for (int half = 0; half < 2; ++half) {
        const signed char* Bx = bexp +
            (((size_t)b*(I/16) + quad)*256 + tw + half*32 + col)*16;

        v4i acc[5][2];
        #pragma unroll
        for (int p = 0; p < 5; ++p)
            #pragma unroll
            for (int nt = 0; nt < 2; ++nt)
                acc[p][nt] = (v4i){0, 0, 0, 0};

        #pragma unroll 1
        for (int s = 0; s < NS; ++s) {
            v4i af[5];
            #pragma unroll
            for (int p = 0; p < 5; ++p)
                af[p] = *(const v4i*)(const void*)(Apg + (size_t)s * 5120 + p * 1024);
            v4i bf[2];
            #pragma unroll
            for (int nt = 0; nt < 2; ++nt)
                bf[nt] = *(const v4i*)(const void*)(Bx + (size_t)s * 16384 + nt * 256);

            #pragma unroll
            for (int nt = 0; nt < 2; ++nt)
                #pragma unroll
                for (int p = 0; p < 5; ++p)
                    acc[p][nt] = __builtin_amdgcn_mfma_i32_16x16x64_i8(
                                     af[p], bf[nt], acc[p][nt], 0, 0, 0);
        }

        // recombine: exact fp64 a into LDS (verified mapping)
        #pragma unroll
        for (int nt = 0; nt < 2; ++nt) {
            const int t = tw + half*32 + nt*16 + col;
            #pragma unroll
            for (int r = 0; r < 4; ++r) {
                double v =            (double)acc[4][nt][r];
                v = v * 256.0 + (double)acc[3][nt][r];
                v = v * 256.0 + (double)acc[2][nt][r];
                v = v * 256.0 + (double)acc[1][nt][r];
                v = v * 256.0 + (double)acc[0][nt][r];
                a_lds[t * 17 + quad*4 + r] = v * inv;
            }
        }
    }

    if (tid < 17) a_lds[256 * 17 + tid] = 0.0;           // zero-guard row
    __syncthreads();                                     // the only barrier

    // ---------------- phase 2: conv (R20-proven serialized body) ------------
    const int o    = tid & 15;
    const int tgrp = tid >> 4;                           // 0..15
    #pragma unroll 1
    for (int pass = 0; pass < 4; ++pass) {
        const int T0b = pass * 64 + tgrp * 4;
        double u0 = 0, u1 = 0, u2 = 0, u3 = 0;
        double w1 = srmE[64], w2 = srmE[65], w3 = srmE[66];   // zero pads
        for (int d = 0; d < 64; d += 4) {
            const int row = T0b - 61 + d;
            const int r0 = (row + 0 < 0) ? 256 : row + 0;
            const int r1 = (row + 1 < 0) ? 256 : row + 1;
            const int r2 = (row + 2 < 0) ? 256 : row + 2;
            const int r3 = (row + 3 < 0) ? 256 : row + 3;
            const double av0 = a_lds[r0 * 17 + o];
            const double av1 = a_lds[r1 * 17 + o];
            const double av2 = a_lds[r2 * 17 + o];
            const double av3 = a_lds[r3 * 17 + o];
            const double n0 = srmE[63 - d], n1 = srmE[62 - d];
            const double n2 = srmE[61 - d], n3 = srmE[60 - d];
            u0 = fma(n0, av0, u0); u1 = fma(w1, av0, u1); u2 = fma(w2, av0, u2); u3 = fma(w3, av0, u3);
            u0 = fma(n1, av1, u0); u1 = fma(n0, av1, u1); u2 = fma(w1, av1, u2); u3 = fma(w2, av1, u3);
            u0 = fma(n2, av2, u0); u1 = fma(n1, av2, u1); u2 = fma(n0, av2, u2); u3 = fma(w1, av2, u3);
            u0 = fma(n3, av3, u0); u1 = fma(n2, av3, u1); u2 = fma(n1, av3, u2); u3 = fma(n0, av3, u3);
            w1 = n3; w2 = n2; w3 = n1;
        }
        double* up = u + ((size_t)b * 256 + T0b) * OS + o0 + o;
        up[0]              = u0;
        up[(size_t)OS]     = u1;
        up[(size_t)OS * 2] = u2;
        up[(size_t)OS * 3] = u3;
    }
}

// ========================== scan (R8/R10-verified core) =====================
// lane = neuron; 256 sequential steps; refractory via 61-bit history mask.
// FINAL=false: ballots -> expanded i8 B-matrix bexp_out[b][g][t][m].
// FINAL=true:  f32 out[b][o][t].
template<bool FINAL>
__global__ __launch_bounds__(256)
void scan_spikes(const double* __restrict__ u, signed char* __restrict__ bexp_out,
                 float* __restrict__ f32_out, int OS)
{
    __shared__ double   ref64[KLEN];
    __shared__ uint32_t blds[8][256];   // 8 KB ballot staging
    const int tid = threadIdx.x;
    if (tid < KLEN) {
        double v = (double)tid / 8.0 * exp(1.0 - (double)tid / 8.0);
        ref64[tid] = (double)(float)(-20.0 * v);
    }
    __syncthreads();

    const int b     = blockIdx.y;
    const int obase = blockIdx.x * 256;
    const int o     = obase + tid;
    const int lane  = tid & 63;
    const int wv    = tid >> 6;
    const double* up = u + (size_t)b * TT * OS + o;

    uint64_t mask = 0;
    double cur0 = up[0], cur1 = up[OS], cur2 = up[2 * (size_t)OS], cur3 = up[3 * (size_t)OS];
    for (int t0 = 0; t0 < TT; t0 += 4) {
        double nx0 = 0, nx1 = 0, nx2 = 0, nx3 = 0;
        if (t0 + 4 < TT) {
            const double* pp = up + (size_t)(t0 + 4) * OS;
            nx0 = pp[0]; nx1 = pp[OS]; nx2 = pp[2 * (size_t)OS]; nx3 = pp[3 * (size_t)OS];
        }
        #pragma unroll
        for (int q = 0; q < 4; ++q) {
            const double uv = (q == 0) ? cur0 : (q == 1) ? cur1 : (q == 2) ? cur2 : cur3;
            uint64_t m = mask;
            double r0 = 0.0, r1 = 0.0;
            while (m) {
                int p = __builtin_ctzll(m); m &= m - 1;
                r0 += ref64[p + 1];
                if (m) { int pq = __builtin_ctzll(m); m &= m - 1; r1 += ref64[pq + 1]; }
            }
            const bool s = (uv + (r0 + r1)) >= THETA;
            const uint64_t bal = __ballot(s);
            if (lane == 0) {
                blds[wv * 2 + 0][t0 + q] = (uint32_t)bal;
                blds[wv * 2 + 1][t0 + q] = (uint32_t)(bal >> 32);
            }
            mask = ((mask << 1) | (s ? 1ull : 0ull)) & ((1ull << 61) - 1ull);
        }
        cur0 = nx0; cur1 = nx1; cur2 = nx2; cur3 = nx3;
    }
    __syncthreads();

    if (!FINAL) {
        // expand ballots to i8 B-matrix: entry g = obase/16 + gl, byte m =
        // bit ((gl&1)*16 + m) of word blds[gl>>1][t]  (i = g*16 + m)
        const int gbase = obase >> 4;
        for (int e = tid; e < 16 * 256; e += 256) {
            const int gl = e >> 8, t = e & 255;
            const uint32_t w = blds[gl >> 1][t];
            const uint32_t h = (w >> ((gl & 1) * 16)) & 0xFFFFu;
            uint32_t uu[4];
            #pragma unroll
            for (int j = 0; j < 4; ++j)
                uu[j] = (((h >> (4*j)) & 0xFu) * 0x00204081u) & 0x01010101u;
            *(uint4*)(bexp_out + (((size_t)b*128 + gbase + gl)*256 + t)*16) =
                *(const uint4*)uu;
        }
    } else {
        for (int ol = 0; ol < 256; ++ol) {
            const uint32_t w = blds[ol >> 5][tid];
            f32_out[((size_t)b * 512 + obase + ol) * TT + tid] =
                (float)((w >> (ol & 31)) & 1u);
        }
    }
}

// ================================ launcher ==================================
extern "C" void kernel_launch(void* const* d_in, const int* in_sizes, int n_in,
                              void* d_out, int out_size, void* d_ws, size_t ws_size,
                              hipStream_t stream)
{
    const float* x  = (const float*)d_in[0];   // [32][1024][256]
    const float* w1 = (const float*)d_in[1];   // [2048][1024]
    const float* w2 = (const float*)d_in[2];   // [512][2048]
    float* out = (float*)d_out;                // [32][512][256]

    char* ws = (char*)d_ws;
    // liveness-based layout (Bexp2 aliases dead P1/Bexp1): total ~158 MB
    signed char* P2    = (signed char*)ws;                      // 5.25 MB
    size_t roff = (size_t)32 * 32 * 5120;                       // 5242880
    signed char* P1    = (signed char*)(ws + roff);             // 10.5 MB
    signed char* Bexp1 = (signed char*)(ws + roff + (size_t)128*16*5120); // 8 MB
    signed char* Bexp2 = (signed char*)(ws + roff);             // 16 MB (alias)
    size_t uoff = roff + (size_t)128*16*5120 + (size_t)32*64*256*16; // 24117248
    double* uBuf = (double*)(ws + uoff);                        // 134 MB

    expand_x<<<dim3(32, 64), 256, 0, stream>>>(x, Bexp1);
    decompose_i8<<<dim3((10485760 + 255)/256), 256, 0, stream>>>(w1, P1, 1024, 10485760);
    decompose_i8<<<dim3((5242880  + 255)/256), 256, 0, stream>>>(w2, P2, 2048, 5242880);

    // layer 1: 1024 -> 2048  (fused gemm+conv: u written directly)
    fused_gc<1024><<<dim3(32, 128), 256, 0, stream>>>(Bexp1, P1, uBuf, 2048);
    scan_spikes<false><<<dim3(8, 32), 256, 0, stream>>>(uBuf, Bexp2, nullptr, 2048);
    // layer 2: 2048 -> 512
    fused_gc<2048><<<dim3(32, 32), 256, 0, stream>>>(Bexp2, P2, uBuf, 512);
    scan_spikes<true><<<dim3(2, 32), 256, 0, stream>>>(uBuf, nullptr, out, 512);
}